// Round 5
// baseline (158.087 us; speedup 1.0000x reference)
//
#include <hip/hip_runtime.h>
#include <cmath>

#define B_    64
#define G_    8
#define DIM_  32
#define E_    8
#define OC_   10
#define LL    4096
#define LP    4094
#define COMBINE_SIZE (B_ * G_ * OC_ * LP)   // 20,961,280

// fast tanh: 1 - 2/(e^{2v}+1); exp overflow/underflow saturates correctly
__device__ __forceinline__ float fast_tanh(float v) {
    const float e = __expf(2.f * v);
    return 1.f - 2.f * __builtin_amdgcn_rcpf(e + 1.f);
}

// ---- repack conv1 weights: w1[g][o][d][t] -> w1t[g][d][o*3+t] (row pad 32)
__global__ void repack_kernel(const float* __restrict__ w1,
                              float* __restrict__ w1t) {
    const int i = blockIdx.x * 256 + threadIdx.x;   // over 8*32*30
    if (i >= G_ * 32 * 30) return;
    const int g = i / 960, r = i - g * 960;
    const int d = r / 30,  s = r - d * 30;
    const int o = s / 3,   t = s - o * 3;
    w1t[g * 1024 + d * 32 + s] = w1[g * 960 + o * 96 + d * 3 + t];
}

// ---------------- gating: logits -> softmax -> top2 -> gates --------------
__global__ void gate_kernel(const float* __restrict__ x,
                            const float* __restrict__ wg,
                            float* __restrict__ gws,    // [B,G,E] gates
                            float* __restrict__ gout) { // [B,E,G] output
    const int b   = blockIdx.x;
    const int tid = threadIdx.x;
    __shared__ float gin[G_ * 160];
    for (int i = tid; i < G_ * 160; i += 64) {
        int g = i / 160, r = i - g * 160;
        int d = r / 5,   t = r - d * 5;
        gin[i] = x[((size_t)b * (G_ * DIM_) + g * DIM_ + d) * LL + (LL - 6 + t)];
    }
    __syncthreads();
    const int g = tid >> 3, e = tid & 7;
    const float* gp = gin + g * 160;
    const float* wp = wg + (size_t)g * 160 * E_ + e;
    float acc = 0.f;
    for (int i = 0; i < 160; ++i) acc = fmaf(gp[i], wp[i * E_], acc);

    float m = acc;
    #pragma unroll
    for (int s = 4; s >= 1; s >>= 1) m = fmaxf(m, __shfl_xor(m, s));
    float p = expf(acc - m);
    float sum = p;
    #pragma unroll
    for (int s = 4; s >= 1; s >>= 1) sum += __shfl_xor(sum, s);
    p /= sum;

    float pv[8];
    const int base = tid & ~7;
    #pragma unroll
    for (int j = 0; j < 8; ++j) pv[j] = __shfl(p, base + j);
    int i1 = 0; float v1 = pv[0];
    #pragma unroll
    for (int j = 1; j < 8; ++j) if (pv[j] > v1) { v1 = pv[j]; i1 = j; }
    int i2 = -1; float v2 = -1.f;
    #pragma unroll
    for (int j = 0; j < 8; ++j) if (j != i1 && pv[j] > v2) { v2 = pv[j]; i2 = j; }
    const float denom = v1 + v2 + 1e-6f;
    const float gate = (e == i1) ? v1 / denom : ((e == i2) ? v2 / denom : 0.f);
    gws[(b * G_ + g) * E_ + e]   = gate;
    gout[b * (E_ * G_) + e * G_ + g] = gate;
}

// ---------------- load-balancing loss (1 block, 64 threads) ---------------
__global__ void loss_kernel(const float* __restrict__ gws,
                            float* __restrict__ loss_out) {
    const int tid = threadIdx.x;   // tid = g*8 + e
    float imp = 0.f, ld = 0.f;
    for (int b = 0; b < B_; ++b) {
        const float v = gws[b * 64 + tid];
        imp += v;
        ld  += (v > 0.f) ? 1.f : 0.f;
    }
    float si = imp, sl = ld;
    #pragma unroll
    for (int msk = 1; msk <= 4; msk <<= 1) { si += __shfl_xor(si, msk); sl += __shfl_xor(sl, msk); }
    const float mi = si * 0.125f, ml = sl * 0.125f;
    float di = imp - mi, dl = ld - ml;
    float vi = di * di, vl = dl * dl;
    #pragma unroll
    for (int msk = 1; msk <= 4; msk <<= 1) { vi += __shfl_xor(vi, msk); vl += __shfl_xor(vl, msk); }
    const float cvi = (vi / 7.f) / (mi * mi + 1e-10f);
    const float cvl = (vl / 7.f) / (ml * ml + 1e-10f);
    float c = ((tid & 7) == 0) ? (cvi + cvl) : 0.f;
    #pragma unroll
    for (int msk = 1; msk < 64; msk <<= 1) c += __shfl_xor(c, msk);
    if (tid == 0) *loss_out = 0.01f * c;
}

// ---------------- main fused conv1 -> tanh -> gated conv2 ------------------
// grid: 2048 blocks = 64(b)*8(g)*4(tile); 256 threads; 4 l per thread.
// __launch_bounds__(256,8) pins VGPR<=64 -> 8 waves/SIMD for TLP latency
// hiding. Loads are naturally-coalesced dwordx4; halo comes from lane+1 via
// __shfl_down (lane 63 does a tiny exec-masked float2 load instead).
__global__ __launch_bounds__(256, 8) void conv_kernel(
        const float* __restrict__ x,
        const float* __restrict__ w1t,   // repacked [g][d][32]
        const float* __restrict__ b1,
        const float* __restrict__ w2, const float* __restrict__ b2,
        const float* __restrict__ gws,
        float* __restrict__ out) {
    const int tid  = threadIdx.x;
    const int lane = tid & 63;
    const int tile = blockIdx.x & 3;
    const int bg   = blockIdx.x >> 2;
    const int g    = bg & 7;
    const int b    = bg >> 3;

    __shared__ float weff[OC_ * OC_];   // [dd][j]
    __shared__ float beff[OC_];

    const float* gp = gws + bg * E_;
    if (tid < 100) {
        const int dd = tid / 10, j = tid - dd * 10;
        float s = 0.f;
        #pragma unroll
        for (int e = 0; e < 8; ++e)
            s = fmaf(gp[e], w2[(g * 80 + dd * 8 + e) * 10 + j], s);
        weff[tid] = s;
    } else if (tid < 110) {
        const int dd = tid - 100;
        float s = 0.f;
        #pragma unroll
        for (int e = 0; e < 8; ++e)
            s = fmaf(gp[e], b2[g * 80 + dd * 8 + e], s);
        beff[dd] = s;
    }
    __syncthreads();

    const int l = tile * 1024 + tid * 4;
    const float* xb  = x + ((size_t)b * 256 + g * 32) * LL + l;
    const float* wgt = w1t + g * 1024;          // wave-uniform base
    const float* b1g = b1 + g * OC_;            // wave-uniform
    const bool l63  = (lane == 63);
    const bool hval = l63 && (l + 5 < LL);      // lane-63 halo load validity

    float acc[10][4];
    #pragma unroll
    for (int o = 0; o < 10; ++o) {
        const float bv = b1g[o];
        #pragma unroll
        for (int k = 0; k < 4; ++k) acc[o][k] = bv;
    }

#define XLOAD(P, H, dd)                                                         \
    P = *reinterpret_cast<const float4*>(xb + (size_t)(dd) * LL);               \
    H = make_float2(0.f, 0.f);                                                  \
    if (hval) H = *reinterpret_cast<const float2*>(xb + (size_t)(dd) * LL + 4);

#define XCOMP(P, H, dd)                                                         \
    {                                                                           \
        float h0 = __shfl_down(P.x, 1);                                         \
        float h1 = __shfl_down(P.y, 1);                                         \
        h0 = l63 ? H.x : h0;                                                    \
        h1 = l63 ? H.y : h1;                                                    \
        const float xs[6] = {P.x, P.y, P.z, P.w, h0, h1};                       \
        const float* wr = wgt + (size_t)(dd) * 32;                              \
        _Pragma("unroll")                                                       \
        for (int o = 0; o < 10; ++o) {                                          \
            const float w0 = wr[o * 3];                                         \
            const float wA = wr[o * 3 + 1];                                     \
            const float wB = wr[o * 3 + 2];                                     \
            _Pragma("unroll")                                                   \
            for (int k = 0; k < 4; ++k)                                         \
                acc[o][k] = fmaf(xs[k + 2], wB,                                 \
                            fmaf(xs[k + 1], wA,                                 \
                            fmaf(xs[k],     w0, acc[o][k])));                   \
        }                                                                       \
    }

    float4 a0; float2 ah;
    float4 c0; float2 ch;
    XLOAD(a0, ah, 0)
    #pragma unroll 1
    for (int d = 0; d < 30; d += 2) {
        XLOAD(c0, ch, d + 1)
        XCOMP(a0, ah, d)
        XLOAD(a0, ah, d + 2)
        XCOMP(c0, ch, d + 1)
    }
    XLOAD(c0, ch, 31)
    XCOMP(a0, ah, 30)
    XCOMP(c0, ch, 31)
#undef XLOAD
#undef XCOMP

    #pragma unroll
    for (int o = 0; o < 10; ++o)
        #pragma unroll
        for (int k = 0; k < 4; ++k)
            acc[o][k] = fast_tanh(acc[o][k]);

    float* ob = out + (size_t)bg * OC_ * LP + l;
    const bool full = (l + 4 <= LP);
    #pragma unroll
    for (int dd = 0; dd < 10; ++dd) {
        const float* wr = weff + dd * 10;
        float r[4];
        const float bv = beff[dd];
        #pragma unroll
        for (int k = 0; k < 4; ++k) r[k] = bv;
        #pragma unroll
        for (int j = 0; j < 10; ++j) {
            const float w = wr[j];
            #pragma unroll
            for (int k = 0; k < 4; ++k) r[k] = fmaf(acc[j][k], w, r[k]);
        }
        float* op = ob + (size_t)dd * LP;
        if (full) {
            *reinterpret_cast<float2*>(op)     = make_float2(r[0], r[1]);
            *reinterpret_cast<float2*>(op + 2) = make_float2(r[2], r[3]);
        } else {
            #pragma unroll
            for (int k = 0; k < 4; ++k)
                if (l + k < LP) op[k] = r[k];
        }
    }
}

extern "C" void kernel_launch(void* const* d_in, const int* in_sizes, int n_in,
                              void* d_out, int out_size, void* d_ws, size_t ws_size,
                              hipStream_t stream) {
    (void)in_sizes; (void)n_in; (void)out_size; (void)ws_size;
    const float* x  = (const float*)d_in[0];
    const float* w1 = (const float*)d_in[1];
    const float* b1 = (const float*)d_in[2];
    const float* w2 = (const float*)d_in[3];
    const float* b2 = (const float*)d_in[4];
    const float* wg = (const float*)d_in[5];
    float* out      = (float*)d_out;
    float* gws      = (float*)d_ws;                         // [B,G,E]
    float* w1t      = (float*)d_ws + B_ * G_ * E_;          // [g][d][32]
    float* loss_out = out + COMBINE_SIZE;
    float* gout     = out + COMBINE_SIZE + 1;

    repack_kernel<<<(G_ * 32 * 30 + 255) / 256, 256, 0, stream>>>(w1, w1t);
    gate_kernel<<<B_, 64, 0, stream>>>(x, wg, gws, gout);
    loss_kernel<<<1, 64, 0, stream>>>(gws, loss_out);
    conv_kernel<<<B_ * G_ * 4, 256, 0, stream>>>(x, w1t, b1, w2, b2, gws, out);
}

// Round 6
// 110.808 us; speedup vs baseline: 1.4267x; 1.4267x over previous
//
#include <hip/hip_runtime.h>
#include <cmath>

#define B_    64
#define G_    8
#define DIM_  32
#define E_    8
#define OC_   10
#define LL    4096
#define LP    4094
#define COMBINE_SIZE (B_ * G_ * OC_ * LP)   // 20,961,280
#define LDSN  4616                          // padded floats per LDS row buffer

// fast tanh: 1 - 2/(e^{2v}+1); exp overflow/underflow saturates correctly
__device__ __forceinline__ float fast_tanh(float v) {
    const float e = __expf(2.f * v);
    return 1.f - 2.f * __builtin_amdgcn_rcpf(e + 1.f);
}

// ---- repack conv1 weights: w1[g][o][d][t] -> w1t[g][d][o*3+t] (row pad 32)
__global__ void repack_kernel(const float* __restrict__ w1,
                              float* __restrict__ w1t) {
    const int i = blockIdx.x * 256 + threadIdx.x;   // over 8*32*30
    if (i >= G_ * 32 * 30) return;
    const int g = i / 960, r = i - g * 960;
    const int d = r / 30,  s = r - d * 30;
    const int o = s / 3,   t = s - o * 3;
    w1t[g * 1024 + d * 32 + s] = w1[g * 960 + o * 96 + d * 3 + t];
}

// ---------------- gating: logits -> softmax -> top2 -> gates --------------
__global__ void gate_kernel(const float* __restrict__ x,
                            const float* __restrict__ wg,
                            float* __restrict__ gws,    // [B,G,E] gates
                            float* __restrict__ gout) { // [B,E,G] output
    const int b   = blockIdx.x;
    const int tid = threadIdx.x;
    __shared__ float gin[G_ * 160];
    for (int i = tid; i < G_ * 160; i += 64) {
        int g = i / 160, r = i - g * 160;
        int d = r / 5,   t = r - d * 5;
        gin[i] = x[((size_t)b * (G_ * DIM_) + g * DIM_ + d) * LL + (LL - 6 + t)];
    }
    __syncthreads();
    const int g = tid >> 3, e = tid & 7;
    const float* gp = gin + g * 160;
    const float* wp = wg + (size_t)g * 160 * E_ + e;
    float acc = 0.f;
    for (int i = 0; i < 160; ++i) acc = fmaf(gp[i], wp[i * E_], acc);

    float m = acc;
    #pragma unroll
    for (int s = 4; s >= 1; s >>= 1) m = fmaxf(m, __shfl_xor(m, s));
    float p = expf(acc - m);
    float sum = p;
    #pragma unroll
    for (int s = 4; s >= 1; s >>= 1) sum += __shfl_xor(sum, s);
    p /= sum;

    float pv[8];
    const int base = tid & ~7;
    #pragma unroll
    for (int j = 0; j < 8; ++j) pv[j] = __shfl(p, base + j);
    int i1 = 0; float v1 = pv[0];
    #pragma unroll
    for (int j = 1; j < 8; ++j) if (pv[j] > v1) { v1 = pv[j]; i1 = j; }
    int i2 = -1; float v2 = -1.f;
    #pragma unroll
    for (int j = 0; j < 8; ++j) if (j != i1 && pv[j] > v2) { v2 = pv[j]; i2 = j; }
    const float denom = v1 + v2 + 1e-6f;
    const float gate = (e == i1) ? v1 / denom : ((e == i2) ? v2 / denom : 0.f);
    gws[(b * G_ + g) * E_ + e]   = gate;
    gout[b * (E_ * G_) + e * G_ + g] = gate;
}

// ---------------- load-balancing loss (1 block, 64 threads) ---------------
__global__ void loss_kernel(const float* __restrict__ gws,
                            float* __restrict__ loss_out) {
    const int tid = threadIdx.x;   // tid = g*8 + e
    float imp = 0.f, ld = 0.f;
    for (int b = 0; b < B_; ++b) {
        const float v = gws[b * 64 + tid];
        imp += v;
        ld  += (v > 0.f) ? 1.f : 0.f;
    }
    float si = imp, sl = ld;
    #pragma unroll
    for (int msk = 1; msk <= 4; msk <<= 1) { si += __shfl_xor(si, msk); sl += __shfl_xor(sl, msk); }
    const float mi = si * 0.125f, ml = sl * 0.125f;
    float di = imp - mi, dl = ld - ml;
    float vi = di * di, vl = dl * dl;
    #pragma unroll
    for (int msk = 1; msk <= 4; msk <<= 1) { vi += __shfl_xor(vi, msk); vl += __shfl_xor(vl, msk); }
    const float cvi = (vi / 7.f) / (mi * mi + 1e-10f);
    const float cvl = (vl / 7.f) / (ml * ml + 1e-10f);
    float c = ((tid & 7) == 0) ? (cvi + cvl) : 0.f;
    #pragma unroll
    for (int msk = 1; msk < 64; msk <<= 1) c += __shfl_xor(c, msk);
    if (tid == 0) *loss_out = 0.01f * c;
}

// ---------------- main fused conv1 -> tanh -> gated conv2 ------------------
// One block per (b,g): 512 blocks x 512 threads, 8 l per thread.
// The block streams its 32 x-rows (512 KB) SEQUENTIALLY through a
// double-buffered LDS row: issue global loads for row d+1, compute row d
// from LDS, ds_write row d+1, one barrier per row. LDS is +1-per-8 padded
// (idx = f + (f>>3)) so b128 reads/writes land at bank stride 9 (conflict
// free). Weights stay wave-uniform scalar loads.
__global__ __launch_bounds__(512, 4) void conv_kernel(
        const float* __restrict__ x,
        const float* __restrict__ w1t,   // repacked [g][d][32]
        const float* __restrict__ b1,
        const float* __restrict__ w2, const float* __restrict__ b2,
        const float* __restrict__ gws,
        float* __restrict__ out) {
    const int tid = threadIdx.x;
    const int bg  = blockIdx.x;          // b*8 + g
    const int g   = bg & 7;

    __shared__ float xsb[2][LDSN];
    __shared__ float weff[OC_ * OC_];    // [dd][j]
    __shared__ float beff[OC_];

    const float* gp = gws + bg * E_;
    if (tid < 100) {
        const int dd = tid / 10, j = tid - dd * 10;
        float s = 0.f;
        #pragma unroll
        for (int e = 0; e < 8; ++e)
            s = fmaf(gp[e], w2[(g * 80 + dd * 8 + e) * 10 + j], s);
        weff[tid] = s;
    } else if (tid < 110) {
        const int dd = tid - 100;
        float s = 0.f;
        #pragma unroll
        for (int e = 0; e < 8; ++e)
            s = fmaf(gp[e], b2[g * 80 + dd * 8 + e], s);
        beff[dd] = s;
    } else if (tid >= 128 && tid < 144) { // zero the halo pad of both buffers
        const int i = tid - 128;
        xsb[i >> 3][4608 + (i & 7)] = 0.f;
    }

    const float* xrow = x + ((size_t)bg * 32) * LL;   // (b*256+g*32) == bg*32
    const float* wgt  = w1t + g * 1024;               // wave-uniform base
    const float* b1g  = b1 + g * OC_;                 // wave-uniform

    float acc[10][8];
    #pragma unroll
    for (int o = 0; o < 10; ++o) {
        const float bv = b1g[o];
        #pragma unroll
        for (int k = 0; k < 8; ++k) acc[o][k] = bv;
    }

    const int fo = tid * 8;      // this thread's float offset within a row
    const int pb = tid * 9;      // padded LDS index base (= fo + (fo>>3))

    // prologue: stage row 0
    float4 ra = *reinterpret_cast<const float4*>(xrow + fo);
    float4 rb = *reinterpret_cast<const float4*>(xrow + fo + 4);
    *reinterpret_cast<float4*>(&xsb[0][pb])     = ra;
    *reinterpret_cast<float4*>(&xsb[0][pb + 4]) = rb;
    __syncthreads();

    #pragma unroll 1
    for (int d = 0; d < 32; ++d) {
        const int cur = d & 1;
        // issue next row's global loads first (latency hides under compute)
        if (d < 31) {
            const float* xr = xrow + (size_t)(d + 1) * LL + fo;
            ra = *reinterpret_cast<const float4*>(xr);
            rb = *reinterpret_cast<const float4*>(xr + 4);
        }
        // compute row d from LDS
        const float* sb = xsb[cur];
        float xw[10];
        *reinterpret_cast<float4*>(&xw[0]) = *reinterpret_cast<const float4*>(&sb[pb]);
        *reinterpret_cast<float4*>(&xw[4]) = *reinterpret_cast<const float4*>(&sb[pb + 4]);
        xw[8] = sb[pb + 9];
        xw[9] = sb[pb + 10];
        const float* wr = wgt + d * 32;
        #pragma unroll
        for (int o = 0; o < 10; ++o) {
            const float w0 = wr[o * 3];
            const float wA = wr[o * 3 + 1];
            const float wB = wr[o * 3 + 2];
            #pragma unroll
            for (int k = 0; k < 8; ++k)
                acc[o][k] = fmaf(xw[k + 2], wB,
                            fmaf(xw[k + 1], wA,
                            fmaf(xw[k],     w0, acc[o][k])));
        }
        // stage row d+1 into the other buffer, then one barrier
        if (d < 31) {
            *reinterpret_cast<float4*>(&xsb[cur ^ 1][pb])     = ra;
            *reinterpret_cast<float4*>(&xsb[cur ^ 1][pb + 4]) = rb;
        }
        __syncthreads();
    }

    #pragma unroll
    for (int o = 0; o < 10; ++o)
        #pragma unroll
        for (int k = 0; k < 8; ++k)
            acc[o][k] = fast_tanh(acc[o][k]);

    float* ob = out + (size_t)bg * OC_ * LP + fo;
    const bool full = (fo + 8 <= LP);
    #pragma unroll
    for (int dd = 0; dd < 10; ++dd) {
        const float* wr = weff + dd * 10;
        float r[8];
        const float bv = beff[dd];
        #pragma unroll
        for (int k = 0; k < 8; ++k) r[k] = bv;
        #pragma unroll
        for (int j = 0; j < 10; ++j) {
            const float w = wr[j];
            #pragma unroll
            for (int k = 0; k < 8; ++k) r[k] = fmaf(acc[j][k], w, r[k]);
        }
        float* op = ob + (size_t)dd * LP;
        if (full) {
            *reinterpret_cast<float2*>(op)     = make_float2(r[0], r[1]);
            *reinterpret_cast<float2*>(op + 2) = make_float2(r[2], r[3]);
            *reinterpret_cast<float2*>(op + 4) = make_float2(r[4], r[5]);
            *reinterpret_cast<float2*>(op + 6) = make_float2(r[6], r[7]);
        } else {
            #pragma unroll
            for (int k = 0; k < 8; ++k)
                if (fo + k < LP) op[k] = r[k];
        }
    }
}

extern "C" void kernel_launch(void* const* d_in, const int* in_sizes, int n_in,
                              void* d_out, int out_size, void* d_ws, size_t ws_size,
                              hipStream_t stream) {
    (void)in_sizes; (void)n_in; (void)out_size; (void)ws_size;
    const float* x  = (const float*)d_in[0];
    const float* w1 = (const float*)d_in[1];
    const float* b1 = (const float*)d_in[2];
    const float* w2 = (const float*)d_in[3];
    const float* b2 = (const float*)d_in[4];
    const float* wg = (const float*)d_in[5];
    float* out      = (float*)d_out;
    float* gws      = (float*)d_ws;                         // [B,G,E]
    float* w1t      = (float*)d_ws + B_ * G_ * E_;          // [g][d][32]
    float* loss_out = out + COMBINE_SIZE;
    float* gout     = out + COMBINE_SIZE + 1;

    repack_kernel<<<(G_ * 32 * 30 + 255) / 256, 256, 0, stream>>>(w1, w1t);
    gate_kernel<<<B_, 64, 0, stream>>>(x, wg, gws, gout);
    loss_kernel<<<1, 64, 0, stream>>>(gws, loss_out);
    conv_kernel<<<B_ * G_, 512, 0, stream>>>(x, w1t, b1, w2, b2, gws, out);
}